// Round 2
// baseline (250.999 us; speedup 1.0000x reference)
//
#include <hip/hip_runtime.h>
#include <hip/hip_cooperative_groups.h>
#include <math.h>

namespace cg = cooperative_groups;

// MemN2N encoder, eval mode.
// story: (M=256, B=16, S=64) int32; C: (4, 50257, 128) fp32; out: (16, 128) fp32.
//
// Insight 1: E_h[b,m,:] = sum_s C[h][story[m,b,s]] is independent of u ->
//            precompute once for h=1..3 (E_0 never needed, see below).
// Insight 2: u starts at 0 -> hop-0 logits are exactly 0 -> softmax exactly
//            uniform -> U0 = mean_m E_1[b,m,:]. C[0] is dead weight.
// Then:  l1 = E1·U0; p1 = softmax(l1); U1 = U0 + E2^T p1
//        l2 = E2·U1; p2 = softmax(l2); U2 = U1 + E3^T p2  -> output.

#define NVOCAB 50257
#define EMB    128
#define NMEM   256
#define NB     16
#define SLEN   64
#define HS     ((size_t)NB * NMEM * EMB)   // one E table: 512K floats

// Scratch as device globals (no ws_size dependence). Every element is
// written before read on every call — no cross-call state.
__device__ float g_E[3 * (size_t)NB * NMEM * EMB];   // E1,E2,E3: 6 MB
__device__ float g_part[NB * 4 * EMB];               // per-(b,chunk) partials
__device__ float g_logits[NB * NMEM];

// ---------------------------------------------------------------------------
// Kernel 1: gather + sentence-sum for tables 1..3 (unchanged from round 1).
// One wave per (b,m) unit; lane owns 2 emb dims. 1024 blocks x 256.
// ---------------------------------------------------------------------------
__global__ __launch_bounds__(256) void embed_sum_kernel(
    const int* __restrict__ story,   // [M][B][S] flat: (m*16+b)*64 + s
    const float* __restrict__ C)     // [4][VOCAB][EMB]
{
    __shared__ int toks[256];
    const int t = threadIdx.x;
    toks[t] = story[blockIdx.x * 256 + t];
    __syncthreads();

    const int wave = t >> 6;
    const int lane = t & 63;
    const int unit = blockIdx.x * 4 + wave;   // unit = m*NB + b
    const int m = unit >> 4;
    const int b = unit & 15;

    const size_t TBL = (size_t)NVOCAB * EMB;
    const float* __restrict__ C1 = C + TBL;
    const float* __restrict__ C2 = C + 2 * TBL;
    const float* __restrict__ C3 = C + 3 * TBL;
    const int dofs = lane * 2;

    float2 a1 = {0.f, 0.f}, a2 = {0.f, 0.f}, a3 = {0.f, 0.f};
    #pragma unroll 8
    for (int i = 0; i < SLEN; ++i) {
        const int tok = toks[wave * 64 + i];
        const size_t off = (size_t)tok * EMB + dofs;
        const float2 v1 = *(const float2*)(C1 + off);
        const float2 v2 = *(const float2*)(C2 + off);
        const float2 v3 = *(const float2*)(C3 + off);
        a1.x += v1.x; a1.y += v1.y;
        a2.x += v2.x; a2.y += v2.y;
        a3.x += v3.x; a3.y += v3.y;
    }

    const size_t eoff = ((size_t)b * NMEM + m) * EMB + dofs;
    *(float2*)(g_E + eoff)          = a1;
    *(float2*)(g_E + HS + eoff)     = a2;
    *(float2*)(g_E + 2 * HS + eoff) = a3;
}

// ---------------------------------------------------------------------------
// Kernel 2: cooperative 3-hop attention. 64 blocks = 16 b x 4 chunks of 64
// memories; 5 grid syncs. Softmax done redundantly per block (deterministic:
// identical inputs and op order in every block of the same b).
// ---------------------------------------------------------------------------
__global__ __launch_bounds__(256) void hops_coop_kernel(float* __restrict__ out)
{
    cg::grid_group grid = cg::this_grid();

    const int t = threadIdx.x;
    const int b = blockIdx.x >> 2;
    const int c = blockIdx.x & 3;          // chunk: memories [c*64, c*64+64)

    const int g  = t >> 5;                 // 8 row-groups of 32 lanes
    const int rl = t & 31;
    const int d4 = rl * 4;                 // float4 column offset
    const int wave = t >> 6;
    const int lane = t & 63;

    __shared__ float u_lds[EMB];
    __shared__ float prob[NMEM];
    __shared__ float pbuf[8][EMB];
    __shared__ float red[8];

    const float* __restrict__ E1 = g_E + (size_t)b * NMEM * EMB;
    const float* __restrict__ E2 = E1 + HS;
    const float* __restrict__ E3 = E2 + HS;
    float* __restrict__ partc = g_part + (b * 4 + c) * EMB;
    const float* __restrict__ partb = g_part + b * 4 * EMB;

    // ---- P0: partial sum of E1 over this block's 64 memories ----
    {
        float4 acc = {0.f, 0.f, 0.f, 0.f};
        #pragma unroll
        for (int j = 0; j < 8; ++j) {
            const int m = c * 64 + j * 8 + g;
            const float4 v = *(const float4*)(E1 + (size_t)m * EMB + d4);
            acc.x += v.x; acc.y += v.y; acc.z += v.z; acc.w += v.w;
        }
        *(float4*)&pbuf[g][d4] = acc;
        __syncthreads();
        if (t < EMB) {
            float s = 0.f;
            #pragma unroll
            for (int gg = 0; gg < 8; ++gg) s += pbuf[gg][t];
            partc[t] = s;
        }
    }
    grid.sync();

    // logits for this chunk: l[m] = EA[m] . u_lds  (2 rows per wave per iter)
    auto logits_phase = [&](const float* __restrict__ EA) {
        const float4 ur = *(const float4*)&u_lds[(lane & 31) * 4];
        #pragma unroll
        for (int i = 0; i < 8; ++i) {
            const int m = c * 64 + wave * 16 + i * 2 + (lane >> 5);
            const float4 v = *(const float4*)(EA + (size_t)m * EMB + (lane & 31) * 4);
            float s = v.x * ur.x + v.y * ur.y + v.z * ur.z + v.w * ur.w;
            #pragma unroll
            for (int o = 16; o >= 1; o >>= 1) s += __shfl_xor(s, o);
            if ((lane & 31) == 0) g_logits[b * NMEM + m] = s;
        }
    };

    // softmax over all 256 logits (redundant per block) + weighted partial
    // sum over this block's 64 memories of EC -> partc
    auto softmax_weight_phase = [&](const float* __restrict__ EC) {
        const float x = g_logits[b * NMEM + t];
        float mx = x;
        #pragma unroll
        for (int o = 32; o >= 1; o >>= 1) mx = fmaxf(mx, __shfl_xor(mx, o));
        if (lane == 0) red[wave] = mx;
        __syncthreads();
        mx = fmaxf(fmaxf(red[0], red[1]), fmaxf(red[2], red[3]));
        const float e = expf(x - mx);
        float sm = e;
        #pragma unroll
        for (int o = 32; o >= 1; o >>= 1) sm += __shfl_xor(sm, o);
        if (lane == 0) red[4 + wave] = sm;
        __syncthreads();
        const float inv = 1.0f / (red[4] + red[5] + red[6] + red[7]);
        prob[t] = e * inv;
        __syncthreads();

        float4 acc = {0.f, 0.f, 0.f, 0.f};
        #pragma unroll
        for (int j = 0; j < 8; ++j) {
            const int m = c * 64 + j * 8 + g;
            const float w = prob[m];
            const float4 v = *(const float4*)(EC + (size_t)m * EMB + d4);
            acc.x += w * v.x; acc.y += w * v.y; acc.z += w * v.z; acc.w += w * v.w;
        }
        __syncthreads();                       // pbuf safe to overwrite
        *(float4*)&pbuf[g][d4] = acc;
        __syncthreads();
        if (t < EMB) {
            float s = 0.f;
            #pragma unroll
            for (int gg = 0; gg < 8; ++gg) s += pbuf[gg][t];
            partc[t] = s;
        }
    };

    // ---- P1: U0 = mean; logits1 = E1 . U0 ----
    if (t < EMB) {
        u_lds[t] = (partb[t] + partb[EMB + t] + partb[2 * EMB + t] +
                    partb[3 * EMB + t]) * (1.0f / 256.0f);
    }
    __syncthreads();
    logits_phase(E1);
    grid.sync();

    // ---- P2: p1 = softmax; partial o1 with E2 ----
    softmax_weight_phase(E2);
    grid.sync();

    // ---- P3: U1 = U0 + o1; logits2 = E2 . U1 ----
    if (t < EMB) {
        u_lds[t] += partb[t] + partb[EMB + t] + partb[2 * EMB + t] +
                    partb[3 * EMB + t];
    }
    __syncthreads();
    logits_phase(E2);
    grid.sync();

    // ---- P4: p2 = softmax; partial o2 with E3 ----
    softmax_weight_phase(E3);
    grid.sync();

    // ---- P5: U2 = U1 + o2 -> out ----
    if (c == 0 && t < EMB) {
        out[b * EMB + t] = u_lds[t] + partb[t] + partb[EMB + t] +
                           partb[2 * EMB + t] + partb[3 * EMB + t];
    }
}

extern "C" void kernel_launch(void* const* d_in, const int* in_sizes, int n_in,
                              void* d_out, int out_size, void* d_ws, size_t ws_size,
                              hipStream_t stream) {
    const int* story = (const int*)d_in[0];     // (256,16,64) int32
    const float* C = (const float*)d_in[1];     // (4,50257,128) fp32
    float* out = (float*)d_out;                 // (16,128) fp32

    embed_sum_kernel<<<1024, 256, 0, stream>>>(story, C);

    void* args[] = {(void*)&out};
    hipLaunchCooperativeKernel((const void*)hops_coop_kernel,
                               dim3(64), dim3(256), args, 0, stream);
}

// Round 3
// 238.613 us; speedup vs baseline: 1.0519x; 1.0519x over previous
//
#include <hip/hip_runtime.h>
#include <hip/hip_cooperative_groups.h>
#include <math.h>

namespace cg = cooperative_groups;

// MemN2N encoder, eval mode.
// story: (M=256, B=16, S=64) int32; C: (4, 50257, 128) fp32; out: (16, 128) fp32.
//
// Insight 1: E_h[b,m,:] = sum_s C[h][story[m,b,s]] is independent of u ->
//            precompute once for h=1..3 (E_0 never needed, see below).
// Insight 2: u starts at 0 -> hop-0 logits are exactly 0 -> softmax exactly
//            uniform -> U0 = mean_m E_1[b,m,:]. C[0] is dead weight.
// Then:  l1 = E1·U0; p1 = softmax(l1); U1 = U0 + E2^T p1
//        l2 = E2·U1; p2 = softmax(l2); U2 = U1 + E3^T p2  -> output.

#define NVOCAB 50257
#define EMB    128
#define NMEM   256
#define NB     16
#define SLEN   64
#define HS     ((size_t)NB * NMEM * EMB)   // one E table: 512K floats

// Scratch as device globals (no ws_size dependence). Every element is
// written before read on every call — no cross-call state.
__device__ float g_E[3 * (size_t)NB * NMEM * EMB];   // E1,E2,E3: 6 MB
__device__ float g_part[NB * 4 * EMB];               // per-(b,chunk) partials
__device__ float g_logits[NB * NMEM];

// ---------------------------------------------------------------------------
// Kernel 1: gather + sentence-sum, one wave per (table, b, m) unit.
// 3072 blocks x 256 threads = 12288 waves -> occupancy no longer grid-capped
// (round 2: 1024 blocks -> 31% occupancy, 3.0 TB/s, latency-bound).
// Summation over s stays strictly sequential per dim -> bit-identical to the
// reference-matching rounds 1-2 (absmax 0.0).
// ---------------------------------------------------------------------------
__global__ __launch_bounds__(256) void embed_sum_kernel(
    const int* __restrict__ story,   // [M][B][S] flat: (m*16+b)*64 + s
    const float* __restrict__ C)     // [4][VOCAB][EMB]
{
    __shared__ int toks[256];
    const int t = threadIdx.x;
    const int grp = blockIdx.x >> 10;          // 0..2 -> table C[grp+1]
    const int ublk = blockIdx.x & 1023;        // unit-block 0..1023
    toks[t] = story[ublk * 256 + t];
    __syncthreads();

    const int wave = t >> 6;
    const int lane = t & 63;
    const int unit = ublk * 4 + wave;          // unit = m*NB + b
    const int m = unit >> 4;
    const int b = unit & 15;
    const int dofs = lane * 2;

    const float* __restrict__ Ct =
        C + (size_t)(grp + 1) * NVOCAB * EMB + dofs;

    float2 acc = {0.f, 0.f};
    #pragma unroll 16
    for (int i = 0; i < SLEN; ++i) {
        const int tok = toks[wave * 64 + i];           // LDS broadcast
        const float2 v = *(const float2*)(Ct + (size_t)tok * EMB);
        acc.x += v.x;
        acc.y += v.y;
    }

    *(float2*)(g_E + (size_t)grp * HS +
               ((size_t)b * NMEM + m) * EMB + dofs) = acc;
}

// ---------------------------------------------------------------------------
// Kernel 2: cooperative 3-hop attention. 64 blocks = 16 b x 4 chunks of 64
// memories; 5 grid syncs. Softmax done redundantly per block (deterministic:
// identical inputs and op order in every block of the same b).
// ---------------------------------------------------------------------------
__global__ __launch_bounds__(256) void hops_coop_kernel(float* __restrict__ out)
{
    cg::grid_group grid = cg::this_grid();

    const int t = threadIdx.x;
    const int b = blockIdx.x >> 2;
    const int c = blockIdx.x & 3;          // chunk: memories [c*64, c*64+64)

    const int g  = t >> 5;                 // 8 row-groups of 32 lanes
    const int rl = t & 31;
    const int d4 = rl * 4;                 // float4 column offset
    const int wave = t >> 6;
    const int lane = t & 63;

    __shared__ float u_lds[EMB];
    __shared__ float prob[NMEM];
    __shared__ float pbuf[8][EMB];
    __shared__ float red[8];

    const float* __restrict__ E1 = g_E + (size_t)b * NMEM * EMB;
    const float* __restrict__ E2 = E1 + HS;
    const float* __restrict__ E3 = E2 + HS;
    float* __restrict__ partc = g_part + (b * 4 + c) * EMB;
    const float* __restrict__ partb = g_part + b * 4 * EMB;

    // ---- P0: partial sum of E1 over this block's 64 memories ----
    {
        float4 acc = {0.f, 0.f, 0.f, 0.f};
        #pragma unroll
        for (int j = 0; j < 8; ++j) {
            const int m = c * 64 + j * 8 + g;
            const float4 v = *(const float4*)(E1 + (size_t)m * EMB + d4);
            acc.x += v.x; acc.y += v.y; acc.z += v.z; acc.w += v.w;
        }
        *(float4*)&pbuf[g][d4] = acc;
        __syncthreads();
        if (t < EMB) {
            float s = 0.f;
            #pragma unroll
            for (int gg = 0; gg < 8; ++gg) s += pbuf[gg][t];
            partc[t] = s;
        }
    }
    grid.sync();

    // logits for this chunk: l[m] = EA[m] . u_lds  (2 rows per wave per iter)
    auto logits_phase = [&](const float* __restrict__ EA) {
        const float4 ur = *(const float4*)&u_lds[(lane & 31) * 4];
        #pragma unroll
        for (int i = 0; i < 8; ++i) {
            const int m = c * 64 + wave * 16 + i * 2 + (lane >> 5);
            const float4 v = *(const float4*)(EA + (size_t)m * EMB + (lane & 31) * 4);
            float s = v.x * ur.x + v.y * ur.y + v.z * ur.z + v.w * ur.w;
            #pragma unroll
            for (int o = 16; o >= 1; o >>= 1) s += __shfl_xor(s, o);
            if ((lane & 31) == 0) g_logits[b * NMEM + m] = s;
        }
    };

    // softmax over all 256 logits (redundant per block) + weighted partial
    // sum over this block's 64 memories of EC -> partc
    auto softmax_weight_phase = [&](const float* __restrict__ EC) {
        const float x = g_logits[b * NMEM + t];
        float mx = x;
        #pragma unroll
        for (int o = 32; o >= 1; o >>= 1) mx = fmaxf(mx, __shfl_xor(mx, o));
        if (lane == 0) red[wave] = mx;
        __syncthreads();
        mx = fmaxf(fmaxf(red[0], red[1]), fmaxf(red[2], red[3]));
        const float e = expf(x - mx);
        float sm = e;
        #pragma unroll
        for (int o = 32; o >= 1; o >>= 1) sm += __shfl_xor(sm, o);
        if (lane == 0) red[4 + wave] = sm;
        __syncthreads();
        const float inv = 1.0f / (red[4] + red[5] + red[6] + red[7]);
        prob[t] = e * inv;
        __syncthreads();

        float4 acc = {0.f, 0.f, 0.f, 0.f};
        #pragma unroll
        for (int j = 0; j < 8; ++j) {
            const int m = c * 64 + j * 8 + g;
            const float w = prob[m];
            const float4 v = *(const float4*)(EC + (size_t)m * EMB + d4);
            acc.x += w * v.x; acc.y += w * v.y; acc.z += w * v.z; acc.w += w * v.w;
        }
        __syncthreads();                       // pbuf safe to overwrite
        *(float4*)&pbuf[g][d4] = acc;
        __syncthreads();
        if (t < EMB) {
            float s = 0.f;
            #pragma unroll
            for (int gg = 0; gg < 8; ++gg) s += pbuf[gg][t];
            partc[t] = s;
        }
    };

    // ---- P1: U0 = mean; logits1 = E1 . U0 ----
    if (t < EMB) {
        u_lds[t] = (partb[t] + partb[EMB + t] + partb[2 * EMB + t] +
                    partb[3 * EMB + t]) * (1.0f / 256.0f);
    }
    __syncthreads();
    logits_phase(E1);
    grid.sync();

    // ---- P2: p1 = softmax; partial o1 with E2 ----
    softmax_weight_phase(E2);
    grid.sync();

    // ---- P3: U1 = U0 + o1; logits2 = E2 . U1 ----
    if (t < EMB) {
        u_lds[t] += partb[t] + partb[EMB + t] + partb[2 * EMB + t] +
                    partb[3 * EMB + t];
    }
    __syncthreads();
    logits_phase(E2);
    grid.sync();

    // ---- P4: p2 = softmax; partial o2 with E3 ----
    softmax_weight_phase(E3);
    grid.sync();

    // ---- P5: U2 = U1 + o2 -> out ----
    if (c == 0 && t < EMB) {
        out[b * EMB + t] = u_lds[t] + partb[t] + partb[EMB + t] +
                           partb[2 * EMB + t] + partb[3 * EMB + t];
    }
}

extern "C" void kernel_launch(void* const* d_in, const int* in_sizes, int n_in,
                              void* d_out, int out_size, void* d_ws, size_t ws_size,
                              hipStream_t stream) {
    const int* story = (const int*)d_in[0];     // (256,16,64) int32
    const float* C = (const float*)d_in[1];     // (4,50257,128) fp32
    float* out = (float*)d_out;                 // (16,128) fp32

    embed_sum_kernel<<<3072, 256, 0, stream>>>(story, C);

    void* args[] = {(void*)&out};
    hipLaunchCooperativeKernel((const void*)hops_coop_kernel,
                               dim3(64), dim3(256), args, 0, stream);
}

// Round 4
// 185.753 us; speedup vs baseline: 1.3513x; 1.2846x over previous
//
#include <hip/hip_runtime.h>
#include <math.h>

// MemN2N encoder, eval mode.
// story: (M=256, B=16, S=64) int32; C: (4, 50257, 128) fp32; out: (16, 128) fp32.
//
// Insight 1: E_h[b,m,:] = sum_s C[h][story[m,b,s]] is independent of u ->
//            precompute once for h=1..3 (E_0 never needed, see below).
// Insight 2: u starts at 0 -> hop-0 logits are exactly 0 -> softmax exactly
//            uniform -> U0 = mean_m E_1[b,m,:]. C[0] is dead weight.
// Then:  l1 = E1·U0; p1 = softmax(l1); U1 = U0 + E2^T p1
//        l2 = E2·U1; p2 = softmax(l2); U2 = U1 + E3^T p2  -> output.
//
// R3 lesson: 5x grid.sync() on a 64-block cooperative launch cost ~10 us each
// (hops_coop ~60-65 us ~= R1's naive 70 us). This round: plain launch,
// 16 blocks x 1024 threads, __syncthreads only, deep unroll for MLP.

#define NVOCAB 50257
#define EMB    128
#define NMEM   256
#define NB     16
#define SLEN   64
#define HS     ((size_t)NB * NMEM * EMB)   // one E table: 512K floats

// E1,E2,E3: 6 MB device-global scratch; fully rewritten every call.
__device__ float g_E[3 * (size_t)NB * NMEM * EMB];

// ---------------------------------------------------------------------------
// Kernel 1: gather + sentence-sum, one wave per (table, b, m) unit.
// 3072 blocks x 256 threads (unchanged from round 3).
// ---------------------------------------------------------------------------
__global__ __launch_bounds__(256) void embed_sum_kernel(
    const int* __restrict__ story,   // [M][B][S] flat: (m*16+b)*64 + s
    const float* __restrict__ C)     // [4][VOCAB][EMB]
{
    __shared__ int toks[256];
    const int t = threadIdx.x;
    const int grp = blockIdx.x >> 10;          // 0..2 -> table C[grp+1]
    const int ublk = blockIdx.x & 1023;        // unit-block 0..1023
    toks[t] = story[ublk * 256 + t];
    __syncthreads();

    const int wave = t >> 6;
    const int lane = t & 63;
    const int unit = ublk * 4 + wave;          // unit = m*NB + b
    const int m = unit >> 4;
    const int b = unit & 15;
    const int dofs = lane * 2;

    const float* __restrict__ Ct =
        C + (size_t)(grp + 1) * NVOCAB * EMB + dofs;

    float2 acc = {0.f, 0.f};
    #pragma unroll 16
    for (int i = 0; i < SLEN; ++i) {
        const int tok = toks[wave * 64 + i];           // LDS broadcast
        const float2 v = *(const float2*)(Ct + (size_t)tok * EMB);
        acc.x += v.x;
        acc.y += v.y;
    }

    *(float2*)(g_E + (size_t)grp * HS +
               ((size_t)b * NMEM + m) * EMB + dofs) = acc;
}

// ---------------------------------------------------------------------------
// Kernel 2: 3-hop attention, one block (1024 threads = 16 waves) per batch.
// Every read-phase is 128 KB coalesced per block with >=16 outstanding
// loads/thread; __syncthreads between phases.
// ---------------------------------------------------------------------------
__global__ __launch_bounds__(1024) void hops_kernel(float* __restrict__ out)
{
    const int b = blockIdx.x;
    const int t = threadIdx.x;
    const int d  = t & 127;        // P0 / o-phase: column
    const int mg = t >> 7;         // P0 / o-phase: 8 groups of 32 memories
    const int mq = t >> 2;         // logits: memory index (0..255)
    const int qq = t & 3;          // logits: quarter of the 128-dim dot

    __shared__ float u[EMB];
    __shared__ float slog[NMEM];
    __shared__ float prob[NMEM];
    __shared__ float pbuf[8][EMB];
    __shared__ float red[8];

    const float* __restrict__ E1 = g_E + (size_t)b * NMEM * EMB;
    const float* __restrict__ E2 = E1 + HS;
    const float* __restrict__ E3 = E2 + HS;

    // ---- P0: u = (1/256) * sum_m E1[m,:] ----
    {
        float acc = 0.f;
        const float* p = E1 + (size_t)(mg * 32) * EMB + d;
        #pragma unroll 16
        for (int j = 0; j < 32; ++j) acc += p[(size_t)j * EMB];
        pbuf[mg][d] = acc;
    }
    __syncthreads();
    if (t < EMB) {
        float s = 0.f;
        #pragma unroll
        for (int g = 0; g < 8; ++g) s += pbuf[g][t];
        u[t] = s * (1.0f / 256.0f);
    }
    __syncthreads();

    #pragma unroll 1
    for (int hop = 0; hop < 2; ++hop) {
        const float* __restrict__ EA = (hop == 0) ? E1 : E2;
        const float* __restrict__ EC = (hop == 0) ? E2 : E3;

        // ---- logits: l[m] = EA[m] . u  (4 threads per m, 32 dims each) ----
        {
            const float* rp = EA + (size_t)mq * EMB + qq * 32;
            float v = 0.f;
            #pragma unroll
            for (int j = 0; j < 8; ++j) {
                const float4 a  = *(const float4*)(rp + j * 4);
                const float4 uu = *(const float4*)(&u[qq * 32 + j * 4]);
                v += a.x * uu.x + a.y * uu.y + a.z * uu.z + a.w * uu.w;
            }
            v += __shfl_xor(v, 1);
            v += __shfl_xor(v, 2);
            if (qq == 0) slog[mq] = v;
        }
        __syncthreads();

        // ---- softmax over 256 (first 4 waves; R1 reduction structure) ----
        if (t < NMEM) {
            const int wv = t >> 6, ln = t & 63;
            const float x = slog[t];
            float mx = x;
            #pragma unroll
            for (int o = 32; o >= 1; o >>= 1) mx = fmaxf(mx, __shfl_xor(mx, o));
            if (ln == 0) red[wv] = mx;
        }
        __syncthreads();
        if (t < NMEM) {
            const int wv = t >> 6, ln = t & 63;
            const float mx = fmaxf(fmaxf(red[0], red[1]), fmaxf(red[2], red[3]));
            const float e = expf(slog[t] - mx);
            float sm = e;
            #pragma unroll
            for (int o = 32; o >= 1; o >>= 1) sm += __shfl_xor(sm, o);
            if (ln == 0) red[4 + wv] = sm;
            prob[t] = e;               // normalized via inv below
        }
        __syncthreads();

        // ---- o[d] = sum_m (prob[m]/Z) * EC[m,d]; u += o ----
        const float inv = 1.0f / (red[4] + red[5] + red[6] + red[7]);
        {
            float acc = 0.f;
            const float* p = EC + (size_t)(mg * 32) * EMB + d;
            #pragma unroll 16
            for (int j = 0; j < 32; ++j)
                acc += prob[mg * 32 + j] * p[(size_t)j * EMB];
            pbuf[mg][d] = acc * inv;
        }
        __syncthreads();
        if (t < EMB) {
            float s = 0.f;
            #pragma unroll
            for (int g = 0; g < 8; ++g) s += pbuf[g][t];
            u[t] += s;
        }
        __syncthreads();
    }

    if (t < EMB) out[b * EMB + t] = u[t];
}

extern "C" void kernel_launch(void* const* d_in, const int* in_sizes, int n_in,
                              void* d_out, int out_size, void* d_ws, size_t ws_size,
                              hipStream_t stream) {
    const int* story = (const int*)d_in[0];     // (256,16,64) int32
    const float* C = (const float*)d_in[1];     // (4,50257,128) fp32
    float* out = (float*)d_out;                 // (16,128) fp32

    embed_sum_kernel<<<3072, 256, 0, stream>>>(story, C);
    hops_kernel<<<NB, 1024, 0, stream>>>(out);
}

// Round 5
// 185.563 us; speedup vs baseline: 1.3526x; 1.0010x over previous
//
#include <hip/hip_runtime.h>
#include <math.h>

// MemN2N encoder, eval mode.
// story: (M=256, B=16, S=64) int32; C: (4, 50257, 128) fp32; out: (16, 128) fp32.
//
// Insight 1: E_h[b,m,:] = sum_s C[h][story[m,b,s]] is independent of u ->
//            precompute once for h=1..3 (E_0 never needed, see below).
// Insight 2: u starts at 0 -> hop-0 logits are exactly 0 -> softmax exactly
//            uniform -> U0 = mean_m E_1[b,m,:]. C[0] is dead weight.
// Then:  l1 = E1·U0; p1 = softmax(l1); U1 = U0 + E2^T p1
//        l2 = E2·U1; p2 = softmax(l2); U2 = U1 + E3^T p2  -> output.
//
// R4 state: harness fills/restores ~95-100 us/iter (fixed), embed ~50, hops ~12.
// R5 lever: embed only — explicit 16-deep load batch (v[16], static indices)
// to force 16 outstanding row-loads per wave; accumulation stays strictly
// s-sequential per dim (bit-identical to rounds 1-4, absmax 0.0).

#define NVOCAB 50257
#define EMB    128
#define NMEM   256
#define NB     16
#define SLEN   64
#define HS     ((size_t)NB * NMEM * EMB)   // one E table: 512K floats

// E1,E2,E3: 6 MB device-global scratch; fully rewritten every call.
__device__ float g_E[3 * (size_t)NB * NMEM * EMB];

// ---------------------------------------------------------------------------
// Kernel 1: gather + sentence-sum, one wave per (table, b, m) unit.
// 3072 blocks x 256 threads. Batched loads: 4 batches of 16 rows; each batch
// issues 16 independent float2 loads before any accumulate.
// ---------------------------------------------------------------------------
__global__ __launch_bounds__(256) void embed_sum_kernel(
    const int* __restrict__ story,   // [M][B][S] flat: (m*16+b)*64 + s
    const float* __restrict__ C)     // [4][VOCAB][EMB]
{
    __shared__ int toks[256];
    const int t = threadIdx.x;
    const int grp = blockIdx.x >> 10;          // 0..2 -> table C[grp+1]
    const int ublk = blockIdx.x & 1023;        // unit-block 0..1023
    toks[t] = story[ublk * 256 + t];
    __syncthreads();

    const int wave = t >> 6;
    const int lane = t & 63;
    const int unit = ublk * 4 + wave;          // unit = m*NB + b
    const int m = unit >> 4;
    const int b = unit & 15;
    const int dofs = lane * 2;

    const float* __restrict__ Ct =
        C + (size_t)(grp + 1) * NVOCAB * EMB + dofs;

    float2 acc = {0.f, 0.f};
    #pragma unroll 1
    for (int i0 = 0; i0 < SLEN; i0 += 16) {
        float2 v[16];
        // issue 16 independent row loads (no accumulate in between)
        #pragma unroll
        for (int j = 0; j < 16; ++j) {
            const int tok = toks[wave * 64 + i0 + j];      // LDS broadcast
            v[j] = *(const float2*)(Ct + (size_t)tok * EMB);
        }
        // accumulate in strict s order (bitwise-stable vs reference)
        #pragma unroll
        for (int j = 0; j < 16; ++j) {
            acc.x += v[j].x;
            acc.y += v[j].y;
        }
    }

    *(float2*)(g_E + (size_t)grp * HS +
               ((size_t)b * NMEM + m) * EMB + dofs) = acc;
}

// ---------------------------------------------------------------------------
// Kernel 2: 3-hop attention, one block (1024 threads = 16 waves) per batch.
// (unchanged from round 4)
// ---------------------------------------------------------------------------
__global__ __launch_bounds__(1024) void hops_kernel(float* __restrict__ out)
{
    const int b = blockIdx.x;
    const int t = threadIdx.x;
    const int d  = t & 127;        // P0 / o-phase: column
    const int mg = t >> 7;         // P0 / o-phase: 8 groups of 32 memories
    const int mq = t >> 2;         // logits: memory index (0..255)
    const int qq = t & 3;          // logits: quarter of the 128-dim dot

    __shared__ float u[EMB];
    __shared__ float slog[NMEM];
    __shared__ float prob[NMEM];
    __shared__ float pbuf[8][EMB];
    __shared__ float red[8];

    const float* __restrict__ E1 = g_E + (size_t)b * NMEM * EMB;
    const float* __restrict__ E2 = E1 + HS;
    const float* __restrict__ E3 = E2 + HS;

    // ---- P0: u = (1/256) * sum_m E1[m,:] ----
    {
        float acc = 0.f;
        const float* p = E1 + (size_t)(mg * 32) * EMB + d;
        #pragma unroll 16
        for (int j = 0; j < 32; ++j) acc += p[(size_t)j * EMB];
        pbuf[mg][d] = acc;
    }
    __syncthreads();
    if (t < EMB) {
        float s = 0.f;
        #pragma unroll
        for (int g = 0; g < 8; ++g) s += pbuf[g][t];
        u[t] = s * (1.0f / 256.0f);
    }
    __syncthreads();

    #pragma unroll 1
    for (int hop = 0; hop < 2; ++hop) {
        const float* __restrict__ EA = (hop == 0) ? E1 : E2;
        const float* __restrict__ EC = (hop == 0) ? E2 : E3;

        // ---- logits: l[m] = EA[m] . u  (4 threads per m, 32 dims each) ----
        {
            const float* rp = EA + (size_t)mq * EMB + qq * 32;
            float v = 0.f;
            #pragma unroll
            for (int j = 0; j < 8; ++j) {
                const float4 a  = *(const float4*)(rp + j * 4);
                const float4 uu = *(const float4*)(&u[qq * 32 + j * 4]);
                v += a.x * uu.x + a.y * uu.y + a.z * uu.z + a.w * uu.w;
            }
            v += __shfl_xor(v, 1);
            v += __shfl_xor(v, 2);
            if (qq == 0) slog[mq] = v;
        }
        __syncthreads();

        // ---- softmax over 256 (first 4 waves) ----
        if (t < NMEM) {
            const int wv = t >> 6, ln = t & 63;
            const float x = slog[t];
            float mx = x;
            #pragma unroll
            for (int o = 32; o >= 1; o >>= 1) mx = fmaxf(mx, __shfl_xor(mx, o));
            if (ln == 0) red[wv] = mx;
        }
        __syncthreads();
        if (t < NMEM) {
            const int wv = t >> 6, ln = t & 63;
            const float mx = fmaxf(fmaxf(red[0], red[1]), fmaxf(red[2], red[3]));
            const float e = expf(slog[t] - mx);
            float sm = e;
            #pragma unroll
            for (int o = 32; o >= 1; o >>= 1) sm += __shfl_xor(sm, o);
            if (ln == 0) red[4 + wv] = sm;
            prob[t] = e;               // normalized via inv below
        }
        __syncthreads();

        // ---- o[d] = sum_m (prob[m]/Z) * EC[m,d]; u += o ----
        const float inv = 1.0f / (red[4] + red[5] + red[6] + red[7]);
        {
            float acc = 0.f;
            const float* p = EC + (size_t)(mg * 32) * EMB + d;
            #pragma unroll 16
            for (int j = 0; j < 32; ++j)
                acc += prob[mg * 32 + j] * p[(size_t)j * EMB];
            pbuf[mg][d] = acc * inv;
        }
        __syncthreads();
        if (t < EMB) {
            float s = 0.f;
            #pragma unroll
            for (int g = 0; g < 8; ++g) s += pbuf[g][t];
            u[t] += s;
        }
        __syncthreads();
    }

    if (t < EMB) out[b * EMB + t] = u[t];
}

extern "C" void kernel_launch(void* const* d_in, const int* in_sizes, int n_in,
                              void* d_out, int out_size, void* d_ws, size_t ws_size,
                              hipStream_t stream) {
    const int* story = (const int*)d_in[0];     // (256,16,64) int32
    const float* C = (const float*)d_in[1];     // (4,50257,128) fp32
    float* out = (float*)d_out;                 // (16,128) fp32

    embed_sum_kernel<<<3072, 256, 0, stream>>>(story, C);
    hops_kernel<<<NB, 1024, 0, stream>>>(out);
}